// Round 5
// baseline (880.391 us; speedup 1.0000x reference)
//
#include <hip/hip_runtime.h>
#include <hip/hip_bf16.h>

#define SEQ 2048
#define BATCH 2
#define NH 16
#define DK 64
#define DM 1024

typedef __bf16 bf16;
typedef __bf16 bf16x8 __attribute__((ext_vector_type(8)));
typedef float f32x4 __attribute__((ext_vector_type(4)));
typedef short s16x4 __attribute__((ext_vector_type(4)));

#define MFMA16(a,b,c) __builtin_amdgcn_mfma_f32_16x16x32_bf16(a,b,c,0,0,0)
#define NEG_BIG (-1.0e30f)
#define SC_LOG2E 0.18033688011112042f   /* 0.125 * log2(e) */

// async global->LDS, 16B per lane. LDS dest must be linear (base + lane*16).
#define GLL16(gsrc, ldst) __builtin_amdgcn_global_load_lds( \
    (const __attribute__((address_space(1))) void*)(gsrc), \
    (__attribute__((address_space(3))) void*)(ldst), 16, 0, 0)

__device__ __forceinline__ bf16x8 ld8(const bf16* p){ return *(const bf16x8*)p; }

// Fragment from chunk-swizzled [128][32] bf16 LDS tile (chunk = 16B = 8 elems).
__device__ __forceinline__ bf16x8 frag_bf16lds(const bf16* Ls, int row, int lq){
    int c = lq ^ (row&3);
    return *(const bf16x8*)((const char*)Ls + row*64 + c*16);
}

// ---------------------------------------------------------------------------
// f32 -> bf16 pre-conversion of Q,K,V,Wq,Wk,Wv (scratch in attn-out region,
// dead until attn_kernel overwrites it).
// ---------------------------------------------------------------------------
__global__ __launch_bounds__(256) void cvt_kernel(
    const float* __restrict__ Q,  const float* __restrict__ K,  const float* __restrict__ V,
    const float* __restrict__ Wq, const float* __restrict__ Wk, const float* __restrict__ Wv,
    bf16* __restrict__ Qb, bf16* __restrict__ Kb, bf16* __restrict__ Vb,
    bf16* __restrict__ Wqb, bf16* __restrict__ Wkb, bf16* __restrict__ Wvb)
{
    const int a = blockIdx.y;
    const float* src = (a==0)?Q:(a==1)?K:(a==2)?V:(a==3)?Wq:(a==4)?Wk:Wv;
    bf16* dst        = (a==0)?Qb:(a==1)?Kb:(a==2)?Vb:(a==3)?Wqb:(a==4)?Wkb:Wvb;
    const int n4 = (a<3) ? (BATCH*SEQ*DM)/4 : (DM*DM)/4;
    for (int i = blockIdx.x*256 + threadIdx.x; i < n4; i += gridDim.x*256){
        f32x4 v = ((const f32x4*)src)[i];
        bf16 o[4];
        #pragma unroll
        for (int j=0;j<4;j++) o[j] = (bf16)v[j];
        ((s16x4*)dst)[i] = *(const s16x4*)o;
    }
}

// Wo -> bf16, runs AFTER attn (writes into q_s, dead by then).
__global__ __launch_bounds__(256) void cvtW_kernel(
    const float* __restrict__ W, bf16* __restrict__ Wb)
{
    const int n4 = (DM*DM)/4;
    for (int i = blockIdx.x*256 + threadIdx.x; i < n4; i += gridDim.x*256){
        f32x4 v = ((const f32x4*)W)[i];
        bf16 o[4];
        #pragma unroll
        for (int j=0;j<4;j++) o[j] = (bf16)v[j];
        ((s16x4*)Wb)[i] = *(const s16x4*)o;
    }
}

// ---------------------------------------------------------------------------
// 2-phase double-buffered 128x128 bf16 GEMM tile body. C = X @ W^T.
// Per k-step: issue global_load_lds into the OTHER buffer, compute current,
// ONE __syncthreads (its vmcnt drain lands after the MFMA block -> overlap).
// ---------------------------------------------------------------------------
__device__ __forceinline__ void stage_tiles(
    const bf16* __restrict__ X, const bf16* __restrict__ W,
    bf16* As, bf16* Bs, int m0, int n0, int k0, int tid)
{
    #pragma unroll
    for (int i=0;i<2;i++){
        int ci  = i*256 + tid;             // 16B chunk id, 0..511
        int row = ci >> 2, ch = ci & 3;
        int gc  = (ch ^ (row&3)) << 3;     // inverse-swizzled src col (elems)
        GLL16(X + (size_t)(m0+row)*DM + k0 + gc, (char*)As + ci*16);
        GLL16(W + (size_t)(n0+row)*DM + k0 + gc, (char*)Bs + ci*16);
    }
}

__device__ __forceinline__ void gemm_tile_db(
    const bf16* __restrict__ X, const bf16* __restrict__ W,
    char* lds, int m0, int n0, int tid, int mt, int nt0,
    int lr, int lq, f32x4 acc[4][4])
{
    bf16* As0 = (bf16*)(lds);
    bf16* Bs0 = (bf16*)(lds + 8192);
    bf16* As1 = (bf16*)(lds + 16384);
    bf16* Bs1 = (bf16*)(lds + 24576);
    stage_tiles(X, W, As0, Bs0, m0, n0, 0, tid);
    __syncthreads();
    for (int k0 = 0; k0 < DM; k0 += 32) {
        bf16 *Ac, *Bc, *An, *Bn;
        if ((k0>>5)&1){ Ac=As1; Bc=Bs1; An=As0; Bn=Bs0; }
        else          { Ac=As0; Bc=Bs0; An=As1; Bn=Bs1; }
        if (k0+32 < DM) stage_tiles(X, W, An, Bn, m0, n0, k0+32, tid);
        bf16x8 af[4], bfr[4];
        #pragma unroll
        for (int mi=0;mi<4;mi++) af[mi]  = frag_bf16lds(Ac, mt  + mi*16 + lr, lq);
        #pragma unroll
        for (int ni=0;ni<4;ni++) bfr[ni] = frag_bf16lds(Bc, nt0 + ni*16 + lr, lq);
        #pragma unroll
        for (int mi=0;mi<4;mi++)
            #pragma unroll
            for (int ni=0;ni<4;ni++)
                acc[mi][ni] = MFMA16(af[mi], bfr[ni], acc[mi][ni]);
        __syncthreads();   // drains the prefetch vmcnt AFTER the MFMA block
    }
}

// ---------------------------------------------------------------------------
// QKV projection. z=0 -> q_s [B,H,S,dk]; z=1 -> k_s; z=2 -> vt_s [B,H,dk,S]
// XCD remap: flat = x + 8y; m = flat&31, n = flat>>5 -> blocks sharing an
// A-panel land on the SAME XCD (id%8 = m%8) -> A read once per XCD.
// ---------------------------------------------------------------------------
__global__ __launch_bounds__(256) void qkv_proj_kernel(
    const bf16* __restrict__ Qb, const bf16* __restrict__ Kb, const bf16* __restrict__ Vb,
    const bf16* __restrict__ Wqb, const bf16* __restrict__ Wkb, const bf16* __restrict__ Wvb,
    bf16* __restrict__ q_s, bf16* __restrict__ k_s, bf16* __restrict__ vt_s)
{
    __shared__ __align__(16) char lds[32768];
    const int z = blockIdx.z;
    const bf16* X = (z==0) ? Qb  : (z==1) ? Kb  : Vb;
    const bf16* W = (z==0) ? Wqb : (z==1) ? Wkb : Wvb;
    bf16* out     = (z==0) ? q_s : (z==1) ? k_s : vt_s;

    const int tid  = threadIdx.x;
    const int lane = tid & 63;
    const int w    = tid >> 6;
    const int lr = lane & 15, lq = lane >> 4;
    const int mt  = (w>>1)*64;
    const int nt0 = (w&1)*64;
    const int flat = blockIdx.x + 8*blockIdx.y;    // 0..255
    const int m0 = (flat & 31) * 128;
    const int n0 = (flat >> 5) * 128;

    f32x4 acc[4][4] = {};
    gemm_tile_db(X, W, lds, m0, n0, tid, mt, nt0, lr, lq, acc);

    if (z == 2) {
        // transpose the 128x128 tile through 32KB swizzled LDS, then write
        // s-contiguous 256B-coalesced rows of vt.
        __syncthreads();
        #pragma unroll
        for (int mi=0;mi<4;mi++)
        #pragma unroll
        for (int ni=0;ni<4;ni++){
            int col  = nt0 + ni*16 + lr;          // tile-local feature col
            int row0 = mt + mi*16 + lq*4;         // tile-local token row (x4)
            bf16 pk[4];
            #pragma unroll
            for (int r=0;r<4;r++) pk[r] = (bf16)acc[mi][ni][r];
            char* dst = lds + col*256 + (((row0>>3) ^ (col&15))<<4) + (row0&7)*2;
            *(s16x4*)dst = *(const s16x4*)pk;
        }
        __syncthreads();
        const int b = m0 >> 11, srow0 = m0 & (SEQ-1);
        #pragma unroll
        for (int j=0;j<8;j++){
            int col = j*16 + (tid>>4);            // 0..127
            int sc  = tid & 15;                   // 8-token chunk in row
            bf16x8 val = *(const bf16x8*)(lds + col*256 + ((sc ^ (col&15))<<4));
            int gcol = n0 + col;
            int h = gcol>>6, dd = gcol&63;
            *(bf16x8*)&out[((size_t)((b*NH+h)*DK+dd))*SEQ + srow0 + sc*8] = val;
        }
    } else {
        #pragma unroll
        for (int mi=0;mi<4;mi++)
        #pragma unroll
        for (int ni=0;ni<4;ni++)
        #pragma unroll
        for (int r=0;r<4;r++) {
            int row = m0 + mt + mi*16 + lq*4 + r;
            int col = n0 + nt0 + ni*16 + lr;
            int b = row >> 11, s = row & (SEQ-1);
            int h = col >> 6,  dd = col & 63;
            out[((size_t)(b*NH + h))*SEQ*DK + (size_t)s*DK + dd] = (bf16)acc[mi][ni][r];
        }
    }
}

// ---------------------------------------------------------------------------
// Attention. 32 queries/wave; block = 2 waves on paired q-tiles (y, 63-y).
// Grid (32 bh, 32): id%8 = bh%8 -> 4 heads/XCD, K+V fits L2.
// Max-free two-pass softmax. Unified causal mask (col>row is false for
// kt<ktmax, so no diagonal peel). Pass 1: K register ping-pong prefetch.
// Pass 2: K prefetched cross-tile; V loaded at body TOP so its latency hides
// under the exp/store section. P via XOR-swizzled LDS (conflict-free b128).
// ---------------------------------------------------------------------------
__device__ __forceinline__ void load_ktile(const bf16* __restrict__ kp,
                                           int kt, int lr, int lq, bf16x8* kf){
    #pragma unroll
    for (int ks=0;ks<2;ks++)
        #pragma unroll
        for (int nt=0;nt<4;nt++)
            kf[ks*4+nt] = ld8(kp + (size_t)(kt*64 + nt*16 + lr)*DK + ks*32 + lq*8);
}

__device__ __forceinline__ void load_vtile(const bf16* __restrict__ vp,
                                           int kt, int lr, int lq, bf16x8* vf){
    #pragma unroll
    for (int ks=0;ks<2;ks++)
        #pragma unroll
        for (int nt=0;nt<4;nt++)
            vf[ks*4+nt] = ld8(vp + (size_t)(nt*16+lr)*SEQ + kt*64 + ks*32 + lq*8);
}

__device__ __forceinline__ void mfma_scores(const bf16x8* qf, const bf16x8* kf, f32x4* s){
    const f32x4 z4 = {0.f,0.f,0.f,0.f};
    #pragma unroll
    for (int nt=0;nt<4;nt++) s[nt] = z4;
    #pragma unroll
    for (int ks=0;ks<2;ks++)
        #pragma unroll
        for (int nt=0;nt<4;nt++)
            s[nt] = MFMA16(qf[ks], kf[ks*4+nt], s[nt]);
}

// pass-1 tile body: prefetch next K into KN, accumulate exp-sums from KC
#define P1_TILE(KT, KC, KN)                                                  \
{                                                                            \
    const int _kt = (KT);                                                    \
    if (_kt < ktmax) load_ktile(kp, _kt+1, lr, lq, (KN));                    \
    _Pragma("unroll")                                                        \
    for (int qi=0;qi<2;qi++){                                                \
        f32x4 s[4];                                                          \
        mfma_scores(qf[qi], (KC), s);                                        \
        _Pragma("unroll")                                                    \
        for (int nt=0;nt<4;nt++)                                             \
            _Pragma("unroll")                                                \
            for (int r=0;r<4;r++){                                           \
                float v = s[nt][r]*SC_LOG2E;                                 \
                if ((_kt*64 + nt*16 + lr) > (qw0 + qi*16 + lq*4 + r))        \
                    v = NEG_BIG;                                             \
                lsum[qi][r] += exp2f(v);                                     \
            }                                                                \
    }                                                                        \
}

// pass-2 tile body: V loads at top (hide under exp/stores), K prefetch,
// normalized attn stores + P LDS + PV accumulate
#define P2_TILE(KT, KC, KN)                                                  \
{                                                                            \
    const int _kt = (KT);                                                    \
    bf16x8 vf[8];                                                            \
    load_vtile(vp, _kt, lr, lq, vf);                                         \
    if (_kt < ktmax) load_ktile(kp, _kt+1, lr, lq, (KN));                    \
    _Pragma("unroll")                                                        \
    for (int qi=0;qi<2;qi++){                                                \
        f32x4 s[4];                                                          \
        mfma_scores(qf[qi], (KC), s);                                        \
        _Pragma("unroll")                                                    \
        for (int nt=0;nt<4;nt++)                                             \
            _Pragma("unroll")                                                \
            for (int r=0;r<4;r++){                                           \
                float v = s[nt][r]*SC_LOG2E;                                 \
                if ((_kt*64 + nt*16 + lr) > (qw0 + qi*16 + lq*4 + r))        \
                    v = NEG_BIG;                                             \
                float p = exp2f(v) * inv_l[qi][r];                           \
                int row = qi*16 + lq*4 + r, col = nt*16 + lr;                \
                ab[(size_t)(qw0 + row)*SEQ + _kt*64 + col] = p;              \
                *(bf16*)(Pw + row*128 + ((col*2) ^ ((row&7)<<4))) = (bf16)p; \
            }                                                                \
    }                                                                        \
    __asm__ __volatile__("" ::: "memory");                                   \
    _Pragma("unroll")                                                        \
    for (int qi=0;qi<2;qi++)                                                 \
        _Pragma("unroll")                                                    \
        for (int ks=0;ks<2;ks++){                                            \
            int prow = qi*16 + lr;                                           \
            bf16x8 pf = *(const bf16x8*)(Pw + prow*128 +                     \
                            ((ks*64 + lq*16) ^ ((prow&7)<<4)));              \
            _Pragma("unroll")                                                \
            for (int nt=0;nt<4;nt++)                                         \
                o[qi][nt] = MFMA16(pf, vf[ks*4+nt], o[qi][nt]);              \
        }                                                                    \
}

__global__ __launch_bounds__(128,2) void attn_kernel(
    const bf16* __restrict__ q_s, const bf16* __restrict__ k_s,
    const bf16* __restrict__ vt_s,
    float* __restrict__ attn_out, bf16* __restrict__ ao)
{
    __shared__ __align__(16) bf16 P[2][32][64];   // XOR-swizzled, 128B rows
    const int bh = blockIdx.x;
    const int lane = threadIdx.x & 63, w = threadIdx.x >> 6;
    const int lr = lane & 15, lq = lane >> 4;
    const int qtile = w ? (63 - (int)blockIdx.y) : (int)blockIdx.y;
    const int qw0   = qtile*32;                   // 32-query tile
    const int ktmax = (qw0 + 31) >> 6;            // diagonal 64-key tile

    const bf16* qp = q_s  + (size_t)bh*SEQ*DK;
    const bf16* kp = k_s  + (size_t)bh*SEQ*DK;
    const bf16* vp = vt_s + (size_t)bh*DK*SEQ;
    float* ab = attn_out + (size_t)bh*SEQ*SEQ;
    char* Pw = (char*)&P[w][0][0];

    bf16x8 qf[2][2];
    #pragma unroll
    for (int qi=0;qi<2;qi++)
        #pragma unroll
        for (int ks=0;ks<2;ks++)
            qf[qi][ks] = ld8(qp + (size_t)(qw0+qi*16+lr)*DK + ks*32 + lq*8);

    bf16x8 kA[8], kB[8];
    float lsum[2][4] = {};

    // ---- pass 1: row exp-sums; K ping-pong prefetch ----
    load_ktile(kp, 0, lr, lq, kA);
    for (int kt=0; kt<=ktmax; kt+=2){
        P1_TILE(kt, kA, kB);
        if (kt+1 <= ktmax) P1_TILE(kt+1, kB, kA);
    }
    float inv_l[2][4];
    #pragma unroll
    for (int qi=0;qi<2;qi++)
        #pragma unroll
        for (int r=0;r<4;r++){
            float t = lsum[qi][r];
            t += __shfl_xor(t,1); t += __shfl_xor(t,2);
            t += __shfl_xor(t,4); t += __shfl_xor(t,8);
            inv_l[qi][r] = 1.0f / t;
        }

    // ---- pass 2: normalized attn stores + O accumulate ----
    f32x4 o[2][4] = {};
    load_ktile(kp, 0, lr, lq, kA);
    for (int kt=0; kt<=ktmax; kt+=2){
        P2_TILE(kt, kA, kB);
        if (kt+1 <= ktmax) P2_TILE(kt+1, kB, kA);
    }

    const int b = bh >> 4, h = bh & 15;
    #pragma unroll
    for (int qi=0;qi<2;qi++)
        #pragma unroll
        for (int nt=0;nt<4;nt++)
            #pragma unroll
            for (int r=0;r<4;r++){
                int qrow = qw0 + qi*16 + lq*4 + r;
                ao[(size_t)(b*SEQ + qrow)*DM + h*64 + nt*16 + lr] = (bf16)o[qi][nt][r];
            }

    // ---- zero-fill this wave's strictly-upper attn columns (32 rows) ----
    int cstart = (ktmax+1)*64;
    if (cstart < SEQ) {
        const f32x4 z4 = {0.f,0.f,0.f,0.f};
        float* rp = ab + (size_t)(qw0 + (lane>>1))*SEQ;   // 2 lanes per row
        for (int c4 = (cstart>>2) + (lane&1); c4 < (SEQ>>2); c4 += 2)
            *(f32x4*)(rp + c4*4) = z4;
    }
}

// ---------------------------------------------------------------------------
// Output projection, pure bf16: out = AO @ Wob^T + bo (out f32).
// ---------------------------------------------------------------------------
__global__ __launch_bounds__(256) void out_proj_kernel(
    const bf16* __restrict__ Xa, const bf16* __restrict__ Wob,
    const float* __restrict__ bo, float* __restrict__ out)
{
    __shared__ __align__(16) char lds[32768];
    const int tid  = threadIdx.x;
    const int lane = tid & 63;
    const int w    = tid >> 6;
    const int lr = lane & 15, lq = lane >> 4;
    const int mt  = (w>>1)*64;
    const int nt0 = (w&1)*64;
    const int flat = blockIdx.x + 8*blockIdx.y;    // 0..255
    const int m0 = (flat & 31) * 128;
    const int n0 = (flat >> 5) * 128;

    f32x4 acc[4][4] = {};
    gemm_tile_db(Xa, Wob, lds, m0, n0, tid, mt, nt0, lr, lq, acc);

    #pragma unroll
    for (int mi=0;mi<4;mi++)
    #pragma unroll
    for (int ni=0;ni<4;ni++)
    #pragma unroll
    for (int r=0;r<4;r++) {
        int row = m0 + mt + mi*16 + lq*4 + r;
        int col = n0 + nt0 + ni*16 + lr;
        out[(size_t)row*DM + col] = acc[mi][ni][r] + bo[col];
    }
}

// ---------------------------------------------------------------------------
extern "C" void kernel_launch(void* const* d_in, const int* in_sizes, int n_in,
                              void* d_out, int out_size, void* d_ws, size_t ws_size,
                              hipStream_t stream)
{
    const float* Q  = (const float*)d_in[0];
    const float* K  = (const float*)d_in[1];
    const float* V  = (const float*)d_in[2];
    const float* Wq = (const float*)d_in[3];
    const float* Wk = (const float*)d_in[4];
    const float* Wv = (const float*)d_in[5];
    const float* Wo = (const float*)d_in[6];
    const float* bo = (const float*)d_in[7];
    float* out = (float*)d_out;

    bf16* ws = (bf16*)d_ws;
    const size_t NTOK = (size_t)BATCH*SEQ*DM;   // 4,194,304 elements
    bf16* q_s  = ws;
    bf16* k_s  = ws + NTOK;
    bf16* vt_s = ws + 2*NTOK;
    bf16* ao   = ws + 3*NTOK;                   // 32 MB of ws total

    // bf16 scratch lives in the attn-output region of d_out (512 MB), which is
    // dead until attn_kernel fully overwrites it (stream-ordered after qkv).
    float* ab  = out + NTOK;
    bf16* Qb   = (bf16*)ab;
    bf16* Kb   = Qb + NTOK;
    bf16* Vb   = Qb + 2*NTOK;
    bf16* Wqb  = Qb + 3*NTOK;
    bf16* Wkb  = Wqb + (size_t)DM*DM;
    bf16* Wvb  = Wqb + 2*(size_t)DM*DM;         // total 30 MB << 512 MB

    // Wob lives in q_s, which is dead after attn_kernel.
    bf16* Wob  = q_s;

    cvt_kernel<<<dim3(256,6), 256, 0, stream>>>(Q,K,V,Wq,Wk,Wv, Qb,Kb,Vb,Wqb,Wkb,Wvb);
    qkv_proj_kernel<<<dim3(8,32,3), 256, 0, stream>>>(Qb,Kb,Vb,Wqb,Wkb,Wvb, q_s,k_s,vt_s);
    attn_kernel<<<dim3(32,32), 128, 0, stream>>>(q_s,k_s,vt_s, ab, ao);
    cvtW_kernel<<<dim3(128), 256, 0, stream>>>(Wo, Wob);
    out_proj_kernel<<<dim3(8,32), 256, 0, stream>>>(ao,Wob,bo,out);
}

// Round 6
// 759.585 us; speedup vs baseline: 1.1590x; 1.1590x over previous
//
#include <hip/hip_runtime.h>
#include <hip/hip_bf16.h>

#define SEQ 2048
#define BATCH 2
#define NH 16
#define DK 64
#define DM 1024

typedef __bf16 bf16;
typedef __bf16 bf16x8 __attribute__((ext_vector_type(8)));
typedef float f32x4 __attribute__((ext_vector_type(4)));
typedef short s16x4 __attribute__((ext_vector_type(4)));

#define MFMA16(a,b,c) __builtin_amdgcn_mfma_f32_16x16x32_bf16(a,b,c,0,0,0)
#define NEG_BIG (-1.0e30f)
#define SC_LOG2E 0.18033688011112042f   /* 0.125 * log2(e) */

// async global->LDS, 16B per lane. LDS dest must be linear (base + lane*16).
#define GLL16(gsrc, ldst) __builtin_amdgcn_global_load_lds( \
    (const __attribute__((address_space(1))) void*)(gsrc), \
    (__attribute__((address_space(3))) void*)(ldst), 16, 0, 0)

__device__ __forceinline__ bf16x8 ld8(const bf16* p){ return *(const bf16x8*)p; }

// Fragment from chunk-swizzled [128][32] bf16 LDS tile (chunk = 16B = 8 elems).
__device__ __forceinline__ bf16x8 frag_bf16lds(const bf16* Ls, int row, int lq){
    int c = lq ^ (row&3);
    return *(const bf16x8*)((const char*)Ls + row*64 + c*16);
}

// ---------------------------------------------------------------------------
// f32 -> bf16 pre-conversion of Q,K,V,Wq,Wk,Wv (scratch in attn-out region,
// dead until attn_kernel overwrites it).
// ---------------------------------------------------------------------------
__global__ __launch_bounds__(256) void cvt_kernel(
    const float* __restrict__ Q,  const float* __restrict__ K,  const float* __restrict__ V,
    const float* __restrict__ Wq, const float* __restrict__ Wk, const float* __restrict__ Wv,
    bf16* __restrict__ Qb, bf16* __restrict__ Kb, bf16* __restrict__ Vb,
    bf16* __restrict__ Wqb, bf16* __restrict__ Wkb, bf16* __restrict__ Wvb)
{
    const int a = blockIdx.y;
    const float* src = (a==0)?Q:(a==1)?K:(a==2)?V:(a==3)?Wq:(a==4)?Wk:Wv;
    bf16* dst        = (a==0)?Qb:(a==1)?Kb:(a==2)?Vb:(a==3)?Wqb:(a==4)?Wkb:Wvb;
    const int n4 = (a<3) ? (BATCH*SEQ*DM)/4 : (DM*DM)/4;
    for (int i = blockIdx.x*256 + threadIdx.x; i < n4; i += gridDim.x*256){
        f32x4 v = ((const f32x4*)src)[i];
        bf16 o[4];
        #pragma unroll
        for (int j=0;j<4;j++) o[j] = (bf16)v[j];
        ((s16x4*)dst)[i] = *(const s16x4*)o;
    }
}

// Wo -> bf16, runs AFTER attn (writes into q_s, dead by then).
__global__ __launch_bounds__(256) void cvtW_kernel(
    const float* __restrict__ W, bf16* __restrict__ Wb)
{
    const int n4 = (DM*DM)/4;
    for (int i = blockIdx.x*256 + threadIdx.x; i < n4; i += gridDim.x*256){
        f32x4 v = ((const f32x4*)W)[i];
        bf16 o[4];
        #pragma unroll
        for (int j=0;j<4;j++) o[j] = (bf16)v[j];
        ((s16x4*)Wb)[i] = *(const s16x4*)o;
    }
}

// ---------------------------------------------------------------------------
// Pure-bf16 128x128 GEMM tile body (m97 structure, single-buffered).
// C = X @ W^T, both inputs [*,1024] bf16 K-contiguous.
// ---------------------------------------------------------------------------
__device__ __forceinline__ void gemm_tile_bf16(
    const bf16* __restrict__ X, const bf16* __restrict__ W,
    bf16* As, bf16* Bs, int m0, int n0, int tid, int mt, int nt0,
    int lr, int lq, f32x4 acc[4][4])
{
    for (int k0 = 0; k0 < DM; k0 += 32) {
        if (k0) __syncthreads();
        #pragma unroll
        for (int i=0;i<2;i++){
            int ci  = i*256 + tid;             // 16B chunk id, 0..511
            int row = ci >> 2, ch = ci & 3;
            int gc  = (ch ^ (row&3)) << 3;     // inverse-swizzled src col (elems)
            GLL16(X + (size_t)(m0+row)*DM + k0 + gc, (char*)As + ci*16);
            GLL16(W + (size_t)(n0+row)*DM + k0 + gc, (char*)Bs + ci*16);
        }
        __syncthreads();
        bf16x8 af[4], bfr[4];
        #pragma unroll
        for (int mi=0;mi<4;mi++) af[mi]  = frag_bf16lds(As, mt  + mi*16 + lr, lq);
        #pragma unroll
        for (int ni=0;ni<4;ni++) bfr[ni] = frag_bf16lds(Bs, nt0 + ni*16 + lr, lq);
        #pragma unroll
        for (int mi=0;mi<4;mi++)
            #pragma unroll
            for (int ni=0;ni<4;ni++)
                acc[mi][ni] = MFMA16(af[mi], bfr[ni], acc[mi][ni]);
    }
}

// ---------------------------------------------------------------------------
// QKV projection. z=0 -> q_s [B,H,S,dk]; z=1 -> k_s; z=2 -> vt_s [B,H,dk,S]
// z==2 epilogue: transpose the 128x128 tile through 32KB swizzled LDS, then
// write s-contiguous 256B-coalesced rows (replaces 8B/4KB-stride scatter).
// ---------------------------------------------------------------------------
__global__ __launch_bounds__(256) void qkv_proj_kernel(
    const bf16* __restrict__ Qb, const bf16* __restrict__ Kb, const bf16* __restrict__ Vb,
    const bf16* __restrict__ Wqb, const bf16* __restrict__ Wkb, const bf16* __restrict__ Wvb,
    bf16* __restrict__ q_s, bf16* __restrict__ k_s, bf16* __restrict__ vt_s)
{
    __shared__ __align__(16) char lds[32768];
    const int z = blockIdx.z;
    const bf16* X = (z==0) ? Qb  : (z==1) ? Kb  : Vb;
    const bf16* W = (z==0) ? Wqb : (z==1) ? Wkb : Wvb;
    bf16* out     = (z==0) ? q_s : (z==1) ? k_s : vt_s;

    const int tid  = threadIdx.x;
    const int lane = tid & 63;
    const int w    = tid >> 6;
    const int lr = lane & 15, lq = lane >> 4;
    const int mt  = (w>>1)*64;
    const int nt0 = (w&1)*64;
    const int m0 = blockIdx.y*128;
    const int n0 = blockIdx.x*128;

    bf16* As = (bf16*)lds;
    bf16* Bs = (bf16*)(lds + 8192);

    f32x4 acc[4][4] = {};
    gemm_tile_bf16(X, W, As, Bs, m0, n0, tid, mt, nt0, lr, lq, acc);

    if (z == 2) {
        __syncthreads();                          // last-tile reads done
        #pragma unroll
        for (int mi=0;mi<4;mi++)
        #pragma unroll
        for (int ni=0;ni<4;ni++){
            int col  = nt0 + ni*16 + lr;          // tile-local feature col
            int row0 = mt + mi*16 + lq*4;         // tile-local token row (x4)
            bf16 pk[4];
            #pragma unroll
            for (int r=0;r<4;r++) pk[r] = (bf16)acc[mi][ni][r];
            char* dst = lds + col*256 + (((row0>>3) ^ (col&15))<<4) + (row0&7)*2;
            *(s16x4*)dst = *(const s16x4*)pk;
        }
        __syncthreads();
        const int b = m0 >> 11, srow0 = m0 & (SEQ-1);
        #pragma unroll
        for (int j=0;j<8;j++){
            int col = j*16 + (tid>>4);            // 0..127
            int sc  = tid & 15;                   // 8-token chunk in row
            bf16x8 val = *(const bf16x8*)(lds + col*256 + ((sc ^ (col&15))<<4));
            int gcol = n0 + col;
            int h = gcol>>6, dd = gcol&63;
            *(bf16x8*)&out[((size_t)((b*NH+h)*DK+dd))*SEQ + srow0 + sc*8] = val;
        }
    } else {
        #pragma unroll
        for (int mi=0;mi<4;mi++)
        #pragma unroll
        for (int ni=0;ni<4;ni++)
        #pragma unroll
        for (int r=0;r<4;r++) {
            int row = m0 + mt + mi*16 + lq*4 + r;
            int col = n0 + nt0 + ni*16 + lr;
            int b = row >> 11, s = row & (SEQ-1);
            int h = col >> 6,  dd = col & 63;
            out[((size_t)(b*NH + h))*SEQ*DK + (size_t)s*DK + dd] = (bf16)acc[mi][ni][r];
        }
    }
}

// ---------------------------------------------------------------------------
// Attention. 32 queries per wave (2x16-row fragments): 8 K-loads + 8 V-loads
// per 64-key tile feed 16 MFMA. Block = 2 waves on paired q-tiles (y, 63-y)
// -> identical work per block. Grid (32 bh, 32): id%8 = bh%8 -> 4 heads/XCD.
// Max-free two-pass softmax (scores bounded -> exp can't overflow f32).
// exp2f + folded log2e scale (v_exp_f32 IS base-2: saves one v_mul per exp).
// P via XOR-swizzled LDS (linear 128B rows, byte ^= (row&7)<<4).
// ---------------------------------------------------------------------------
__device__ __forceinline__ void load_ktile(const bf16* __restrict__ kp,
                                           int kt, int lr, int lq, bf16x8* kf){
    #pragma unroll
    for (int ks=0;ks<2;ks++)
        #pragma unroll
        for (int nt=0;nt<4;nt++)
            kf[ks*4+nt] = ld8(kp + (size_t)(kt*64 + nt*16 + lr)*DK + ks*32 + lq*8);
}

__device__ __forceinline__ void mfma_scores(const bf16x8* qf, const bf16x8* kf, f32x4* s){
    const f32x4 z4 = {0.f,0.f,0.f,0.f};
    #pragma unroll
    for (int nt=0;nt<4;nt++) s[nt] = z4;
    #pragma unroll
    for (int ks=0;ks<2;ks++)
        #pragma unroll
        for (int nt=0;nt<4;nt++)
            s[nt] = MFMA16(qf[ks], kf[ks*4+nt], s[nt]);
}

__global__ __launch_bounds__(128,2) void attn_kernel(
    const bf16* __restrict__ q_s, const bf16* __restrict__ k_s,
    const bf16* __restrict__ vt_s,
    float* __restrict__ attn_out, bf16* __restrict__ ao)
{
    __shared__ __align__(16) bf16 P[2][32][64];   // XOR-swizzled, 128B rows
    const int bh = blockIdx.x;
    const int lane = threadIdx.x & 63, w = threadIdx.x >> 6;
    const int lr = lane & 15, lq = lane >> 4;
    const int qtile = w ? (63 - (int)blockIdx.y) : (int)blockIdx.y;
    const int qw0   = qtile*32;                   // 32-query tile
    const int ktmax = (qw0 + 31) >> 6;            // diagonal 64-key tile

    const bf16* qp = q_s  + (size_t)bh*SEQ*DK;
    const bf16* kp = k_s  + (size_t)bh*SEQ*DK;
    const bf16* vp = vt_s + (size_t)bh*DK*SEQ;
    float* ab = attn_out + (size_t)bh*SEQ*SEQ;
    char* Pw = (char*)&P[w][0][0];

    bf16x8 qf[2][2];
    #pragma unroll
    for (int qi=0;qi<2;qi++)
        #pragma unroll
        for (int ks=0;ks<2;ks++)
            qf[qi][ks] = ld8(qp + (size_t)(qw0+qi*16+lr)*DK + ks*32 + lq*8);

    // ---- pass 1: per-lane partial exp-sums; K double-buffered ----
    float lsum[2][4] = {};
    bf16x8 kf[8];
    load_ktile(kp, 0, lr, lq, kf);
    for (int kt=0; kt<ktmax; kt++) {              // full (unmasked) tiles
        bf16x8 kn[8];
        load_ktile(kp, kt+1, lr, lq, kn);         // prefetch next tile
        #pragma unroll
        for (int qi=0;qi<2;qi++){
            f32x4 s[4];
            mfma_scores(qf[qi], kf, s);
            #pragma unroll
            for (int nt=0;nt<4;nt++)
                #pragma unroll
                for (int r=0;r<4;r++)
                    lsum[qi][r] += exp2f(s[nt][r]*SC_LOG2E);
        }
        #pragma unroll
        for (int i=0;i<8;i++) kf[i] = kn[i];
    }
    {   // diagonal tile (masked)
        #pragma unroll
        for (int qi=0;qi<2;qi++){
            f32x4 s[4];
            mfma_scores(qf[qi], kf, s);
            #pragma unroll
            for (int nt=0;nt<4;nt++)
                #pragma unroll
                for (int r=0;r<4;r++){
                    float v = s[nt][r]*SC_LOG2E;
                    if ((ktmax*64 + nt*16 + lr) > (qw0 + qi*16 + lq*4 + r)) v = NEG_BIG;
                    lsum[qi][r] += exp2f(v);
                }
        }
    }
    float inv_l[2][4];
    #pragma unroll
    for (int qi=0;qi<2;qi++)
        #pragma unroll
        for (int r=0;r<4;r++){
            float t = lsum[qi][r];
            t += __shfl_xor(t,1); t += __shfl_xor(t,2);
            t += __shfl_xor(t,4); t += __shfl_xor(t,8);
            inv_l[qi][r] = 1.0f / t;
        }

    // ---- pass 2: normalized attn stores + O accumulate ----
    f32x4 o[2][4] = {};
    for (int kt=0; kt<=ktmax; kt++) {
        load_ktile(kp, kt, lr, lq, kf);
        bf16x8 vf[8];                              // hoisted V loads
        #pragma unroll
        for (int ks=0;ks<2;ks++)
            #pragma unroll
            for (int nt=0;nt<4;nt++)
                vf[ks*4+nt] = ld8(vp + (size_t)(nt*16+lr)*SEQ + kt*64 + ks*32 + lq*8);
        #pragma unroll
        for (int qi=0;qi<2;qi++){
            f32x4 s[4];
            mfma_scores(qf[qi], kf, s);
            if (kt < ktmax) {
                #pragma unroll
                for (int nt=0;nt<4;nt++)
                    #pragma unroll
                    for (int r=0;r<4;r++){
                        float p = exp2f(s[nt][r]*SC_LOG2E) * inv_l[qi][r];
                        int row = qi*16 + lq*4 + r, col = nt*16 + lr;
                        ab[(size_t)(qw0 + row)*SEQ + kt*64 + col] = p;
                        *(bf16*)(Pw + row*128 + ((col*2) ^ ((row&7)<<4))) = (bf16)p;
                    }
            } else {
                #pragma unroll
                for (int nt=0;nt<4;nt++)
                    #pragma unroll
                    for (int r=0;r<4;r++){
                        float v = s[nt][r]*SC_LOG2E;
                        if ((kt*64 + nt*16 + lr) > (qw0 + qi*16 + lq*4 + r)) v = NEG_BIG;
                        float p = exp2f(v) * inv_l[qi][r];
                        int row = qi*16 + lq*4 + r, col = nt*16 + lr;
                        ab[(size_t)(qw0 + row)*SEQ + kt*64 + col] = p;
                        *(bf16*)(Pw + row*128 + ((col*2) ^ ((row&7)<<4))) = (bf16)p;
                    }
            }
        }
        __asm__ __volatile__("" ::: "memory");     // keep LDS writes before reads
        #pragma unroll
        for (int qi=0;qi<2;qi++)
            #pragma unroll
            for (int ks=0;ks<2;ks++){
                int row = qi*16 + lr;
                bf16x8 pf = *(const bf16x8*)(Pw + row*128
                                + ((ks*64 + lq*16) ^ ((row&7)<<4)));  // A-layout
                #pragma unroll
                for (int nt=0;nt<4;nt++)
                    o[qi][nt] = MFMA16(pf, vf[ks*4+nt], o[qi][nt]);
            }
    }

    const int b = bh >> 4, h = bh & 15;
    #pragma unroll
    for (int qi=0;qi<2;qi++)
        #pragma unroll
        for (int nt=0;nt<4;nt++)
            #pragma unroll
            for (int r=0;r<4;r++){
                int qrow = qw0 + qi*16 + lq*4 + r;
                ao[(size_t)(b*SEQ + qrow)*DM + h*64 + nt*16 + lr] = (bf16)o[qi][nt][r];
            }

    // ---- zero-fill this wave's strictly-upper attn columns (32 rows) ----
    int cstart = (ktmax+1)*64;
    if (cstart < SEQ) {
        const f32x4 z4 = {0.f,0.f,0.f,0.f};
        float* rp = ab + (size_t)(qw0 + (lane>>1))*SEQ;   // 2 lanes per row
        for (int c4 = (cstart>>2) + (lane&1); c4 < (SEQ>>2); c4 += 2)
            *(f32x4*)(rp + c4*4) = z4;
    }
}

// ---------------------------------------------------------------------------
// Output projection, pure bf16: out = AO @ Wob^T + bo (out f32).
// ---------------------------------------------------------------------------
__global__ __launch_bounds__(256) void out_proj_kernel(
    const bf16* __restrict__ Xa, const bf16* __restrict__ Wob,
    const float* __restrict__ bo, float* __restrict__ out)
{
    __shared__ __align__(16) bf16 As[128*32];
    __shared__ __align__(16) bf16 Bs[128*32];
    const int tid  = threadIdx.x;
    const int lane = tid & 63;
    const int w    = tid >> 6;
    const int lr = lane & 15, lq = lane >> 4;
    const int mt  = (w>>1)*64;
    const int nt0 = (w&1)*64;
    const int m0 = blockIdx.y*128;
    const int n0 = blockIdx.x*128;

    f32x4 acc[4][4] = {};
    gemm_tile_bf16(Xa, Wob, As, Bs, m0, n0, tid, mt, nt0, lr, lq, acc);

    #pragma unroll
    for (int mi=0;mi<4;mi++)
    #pragma unroll
    for (int ni=0;ni<4;ni++)
    #pragma unroll
    for (int r=0;r<4;r++) {
        int row = m0 + mt + mi*16 + lq*4 + r;
        int col = n0 + nt0 + ni*16 + lr;
        out[(size_t)row*DM + col] = acc[mi][ni][r] + bo[col];
    }
}

// ---------------------------------------------------------------------------
extern "C" void kernel_launch(void* const* d_in, const int* in_sizes, int n_in,
                              void* d_out, int out_size, void* d_ws, size_t ws_size,
                              hipStream_t stream)
{
    const float* Q  = (const float*)d_in[0];
    const float* K  = (const float*)d_in[1];
    const float* V  = (const float*)d_in[2];
    const float* Wq = (const float*)d_in[3];
    const float* Wk = (const float*)d_in[4];
    const float* Wv = (const float*)d_in[5];
    const float* Wo = (const float*)d_in[6];
    const float* bo = (const float*)d_in[7];
    float* out = (float*)d_out;

    bf16* ws = (bf16*)d_ws;
    const size_t NTOK = (size_t)BATCH*SEQ*DM;   // 4,194,304 elements
    bf16* q_s  = ws;
    bf16* k_s  = ws + NTOK;
    bf16* vt_s = ws + 2*NTOK;
    bf16* ao   = ws + 3*NTOK;                   // 32 MB of ws total

    // bf16 scratch lives in the attn-output region of d_out (512 MB), which is
    // dead until attn_kernel fully overwrites it (stream-ordered after qkv).
    float* ab  = out + NTOK;
    bf16* Qb   = (bf16*)ab;
    bf16* Kb   = Qb + NTOK;
    bf16* Vb   = Qb + 2*NTOK;
    bf16* Wqb  = Qb + 3*NTOK;
    bf16* Wkb  = Wqb + (size_t)DM*DM;
    bf16* Wvb  = Wqb + 2*(size_t)DM*DM;         // total 30 MB << 512 MB

    // Wob lives in q_s, which is dead after attn_kernel.
    bf16* Wob  = q_s;

    cvt_kernel<<<dim3(256,6), 256, 0, stream>>>(Q,K,V,Wq,Wk,Wv, Qb,Kb,Vb,Wqb,Wkb,Wvb);
    qkv_proj_kernel<<<dim3(8,32,3), 256, 0, stream>>>(Qb,Kb,Vb,Wqb,Wkb,Wvb, q_s,k_s,vt_s);
    attn_kernel<<<dim3(32,32), 128, 0, stream>>>(q_s,k_s,vt_s, ab, ao);
    cvtW_kernel<<<dim3(128), 256, 0, stream>>>(Wo, Wob);
    out_proj_kernel<<<dim3(8,32), 256, 0, stream>>>(ao,Wob,bo,out);
}